// Round 1
// baseline (1001.078 us; speedup 1.0000x reference)
//
#include <hip/hip_runtime.h>
#include <stdint.h>

typedef short short8 __attribute__((ext_vector_type(8)));
typedef float f32x4 __attribute__((ext_vector_type(4)));

#define N_NODES 8192
#define IN_DIM 20000
#define HIDDEN 256
#define LATENT 64
#define N_EDGES 262144
#define K_STEPS 625
#define SPLIT0_STEPS 312
#define RECON_ELEMS (8192LL * 20000LL)
#define WD2T_ROWS 20096

static __device__ __forceinline__ unsigned short f2bf(float f) {
  union { float f; unsigned int u; } v;
  v.f = f;
  unsigned int u = v.u;
  return (unsigned short)((u + 0x7FFFu + ((u >> 16) & 1u)) >> 16);  // RNE
}

// ----------------- graph prep: degree, scan, CSR fill -----------------
__global__ void k_count(const int* __restrict__ col, int* __restrict__ cnt) {
  int e = blockIdx.x * 256 + threadIdx.x;
  if (e < N_EDGES) atomicAdd(&cnt[col[e]], 1);
}

__global__ void k_dinv(const int* __restrict__ cnt, float* __restrict__ dinv) {
  int i = blockIdx.x * 256 + threadIdx.x;
  if (i < N_NODES) dinv[i] = rsqrtf((float)(cnt[i] + 1));  // +1 self loop
}

__global__ void k_scan(const int* __restrict__ cnt, int* __restrict__ offs,
                       int* __restrict__ cursor) {
  __shared__ int ps[256];
  int t = threadIdx.x;
  int local[32];
  int s = 0;
#pragma unroll
  for (int i = 0; i < 32; ++i) { local[i] = cnt[t * 32 + i]; s += local[i]; }
  ps[t] = s;
  __syncthreads();
  for (int d = 1; d < 256; d <<= 1) {
    int v = (t >= d) ? ps[t - d] : 0;
    __syncthreads();
    ps[t] += v;
    __syncthreads();
  }
  int pre = (t == 0) ? 0 : ps[t - 1];
#pragma unroll
  for (int i = 0; i < 32; ++i) {
    offs[t * 32 + i] = pre;
    cursor[t * 32 + i] = pre;
    pre += local[i];
  }
  if (t == 255) offs[N_NODES] = pre;
}

__global__ void k_fill(const int* __restrict__ row, const int* __restrict__ col,
                       int* __restrict__ cursor, int* __restrict__ csr_src) {
  int e = blockIdx.x * 256 + threadIdx.x;
  if (e < N_EDGES) {
    int c = col[e];
    int pos = atomicAdd(&cursor[c], 1);
    csr_src[pos] = row[e];
  }
}

// ------- pack w_gcn [20000][256] f32 -> tiles [kstep][n=256][k=32] bf16 -------
__global__ void k_pack_wgcn(const float* __restrict__ w, unsigned short* __restrict__ pk) {
  int s = blockIdx.x;   // 625 k-steps
  int t = threadIdx.x;  // n = t
  int k0 = s * 32;
  unsigned int packed[16];
#pragma unroll
  for (int j = 0; j < 16; ++j) {
    float a = w[(size_t)(k0 + 2 * j) * HIDDEN + t];
    float b = w[(size_t)(k0 + 2 * j + 1) * HIDDEN + t];
    packed[j] = (unsigned)f2bf(a) | ((unsigned)f2bf(b) << 16);
  }
  uint4* dst = (uint4*)(pk + ((size_t)s * HIDDEN + t) * 32);
#pragma unroll
  for (int j = 0; j < 4; ++j)
    dst[j] = make_uint4(packed[4 * j], packed[4 * j + 1], packed[4 * j + 2], packed[4 * j + 3]);
}

// ------- transpose w_d2 [256][20000] f32 -> [20096][256] bf16 (zero-padded) -------
__global__ void k_twd2(const float* __restrict__ wd2, unsigned short* __restrict__ wd2t) {
  __shared__ float tile[HIDDEN * 64];  // [k][n_local], 64 KB
  int n0 = blockIdx.x * 64;            // 314 blocks
  int t = threadIdx.x;
  int tk = t >> 6;   // 0..3
  int tn = t & 63;
#pragma unroll 4
  for (int kb = 0; kb < 64; ++kb) {
    int k = kb * 4 + tk;
    int n = n0 + tn;
    tile[k * 64 + tn] = (n < IN_DIM) ? wd2[(size_t)k * IN_DIM + n] : 0.0f;
  }
  __syncthreads();
  int rl = t >> 2;   // out row local 0..63
  int q = t & 3;     // k quarter
  unsigned int packed[32];
#pragma unroll
  for (int j = 0; j < 32; ++j) {
    float a = tile[(q * 64 + 2 * j) * 64 + rl];
    float b = tile[(q * 64 + 2 * j + 1) * 64 + rl];
    packed[j] = (unsigned)f2bf(a) | ((unsigned)f2bf(b) << 16);
  }
  uint4* dst = (uint4*)(wd2t + (size_t)(n0 + rl) * HIDDEN + q * 64);
#pragma unroll
  for (int j = 0; j < 8; ++j)
    dst[j] = make_uint4(packed[4 * j], packed[4 * j + 1], packed[4 * j + 2], packed[4 * j + 3]);
}

// ----------------- GEMM1: h0p[split] = x @ w_gcn (bf16 MFMA) -----------------
// tile 32x256, BK=32, split-K=2, grid (256,2), 256 threads (4 waves)
__global__ __launch_bounds__(256, 2)
void k_gemm1(const float* __restrict__ x, const unsigned short* __restrict__ wpk,
             float* __restrict__ h0p) {
  const int m0 = blockIdx.x * 32;
  const int split = blockIdx.y;
  const int s_beg = split ? SPLIT0_STEPS : 0;
  const int s_end = split ? K_STEPS : SPLIT0_STEPS;

  const int t = threadIdx.x;
  const int lane = t & 63;
  const int w = t >> 6;
  const int lr = lane & 15;
  const int lg = lane >> 4;

  __shared__ unsigned short Alds[2][32 * 40];   // rows padded to 40 (2-way = free)
  __shared__ unsigned short Blds[2][256 * 32];  // XOR-swizzled 16B chunks

  const int arow = t >> 3;
  const int ak = (t & 7) * 4;
  const float* xrow = x + (size_t)(m0 + arow) * IN_DIM + ak;
  const int bsw = ((t ^ (t >> 2)) & 3);

  f32x4 acc[2][4];
#pragma unroll
  for (int i = 0; i < 2; ++i)
#pragma unroll
    for (int j = 0; j < 4; ++j) acc[i][j] = (f32x4){0.f, 0.f, 0.f, 0.f};

  float4 areg;
  uint4 breg0, breg1, breg2, breg3;

  // prologue: load + stage step s_beg into buf 0
  areg = *(const float4*)(xrow + (size_t)s_beg * 32);
  {
    const uint4* bp = (const uint4*)(wpk + ((size_t)s_beg * 256 + t) * 32);
    breg0 = bp[0]; breg1 = bp[1]; breg2 = bp[2]; breg3 = bp[3];
  }
  {
    uint2 ap;
    ap.x = (unsigned)f2bf(areg.x) | ((unsigned)f2bf(areg.y) << 16);
    ap.y = (unsigned)f2bf(areg.z) | ((unsigned)f2bf(areg.w) << 16);
    *(uint2*)&Alds[0][arow * 40 + ak] = ap;
    uint4* br = (uint4*)&Blds[0][t * 32];
    br[0 ^ bsw] = breg0; br[1 ^ bsw] = breg1; br[2 ^ bsw] = breg2; br[3 ^ bsw] = breg3;
  }
  __syncthreads();

  int cur = 0;
  for (int s = s_beg; s < s_end; ++s) {
    bool more = (s + 1 < s_end);
    if (more) {
      areg = *(const float4*)(xrow + (size_t)(s + 1) * 32);
      const uint4* bp = (const uint4*)(wpk + ((size_t)(s + 1) * 256 + t) * 32);
      breg0 = bp[0]; breg1 = bp[1]; breg2 = bp[2]; breg3 = bp[3];
    }
    {
      short8 a0 = *(const short8*)&Alds[cur][lr * 40 + lg * 8];
      short8 a1 = *(const short8*)&Alds[cur][(16 + lr) * 40 + lg * 8];
#pragma unroll
      for (int ct = 0; ct < 4; ++ct) {
        int n = w * 64 + ct * 16 + lr;
        int sw = ((n ^ (n >> 2)) & 3);
        short8 b = *(const short8*)&Blds[cur][n * 32 + ((lg ^ sw) * 8)];
        acc[0][ct] = __builtin_amdgcn_mfma_f32_16x16x32_bf16(a0, b, acc[0][ct], 0, 0, 0);
        acc[1][ct] = __builtin_amdgcn_mfma_f32_16x16x32_bf16(a1, b, acc[1][ct], 0, 0, 0);
      }
    }
    if (more) {
      __syncthreads();
      int nb = cur ^ 1;
      uint2 ap;
      ap.x = (unsigned)f2bf(areg.x) | ((unsigned)f2bf(areg.y) << 16);
      ap.y = (unsigned)f2bf(areg.z) | ((unsigned)f2bf(areg.w) << 16);
      *(uint2*)&Alds[nb][arow * 40 + ak] = ap;
      uint4* br = (uint4*)&Blds[nb][t * 32];
      br[0 ^ bsw] = breg0; br[1 ^ bsw] = breg1; br[2 ^ bsw] = breg2; br[3 ^ bsw] = breg3;
      __syncthreads();
      cur = nb;
    }
  }

  float* outp = h0p + (size_t)split * (N_NODES * HIDDEN) + (size_t)m0 * HIDDEN;
#pragma unroll
  for (int mt = 0; mt < 2; ++mt)
#pragma unroll
    for (int ct = 0; ct < 4; ++ct) {
      int col = w * 64 + ct * 16 + lr;
#pragma unroll
      for (int r = 0; r < 4; ++r) {
        int rowi = mt * 16 + lg * 4 + r;
        outp[rowi * HIDDEN + col] = acc[mt][ct][r];
      }
    }
}

__global__ void k_sum(const float* __restrict__ p, float* __restrict__ h0) {
  int i = blockIdx.x * 256 + threadIdx.x;
  float4 a = ((const float4*)p)[i];
  float4 b = ((const float4*)p)[i + (N_NODES * HIDDEN / 4)];
  float4 r;
  r.x = a.x + b.x; r.y = a.y + b.y; r.z = a.z + b.z; r.w = a.w + b.w;
  ((float4*)h0)[i] = r;
}

// ------------- GCN aggregate (CSR gather) + bias + relu -------------
__global__ void k_agg(const float* __restrict__ h0, const float* __restrict__ dinv,
                      const int* __restrict__ offs, const int* __restrict__ csr_src,
                      const float* __restrict__ bias, float* __restrict__ hrelu) {
  int c = blockIdx.x;
  int t = threadIdx.x;
  float dc = dinv[c];
  float acc = h0[(size_t)c * HIDDEN + t] * dc * dc;  // self loop
  int beg = offs[c], end = offs[c + 1];
  for (int i = beg; i < end; ++i) {
    int r = csr_src[i];
    float wgt = dinv[r] * dc;
    acc += h0[(size_t)r * HIDDEN + t] * wgt;
  }
  float v = acc + bias[t];
  hrelu[(size_t)c * HIDDEN + t] = v > 0.f ? v : 0.f;
}

// ------------- encoder: latent = relu_h @ w_enc + b_enc (fp32) -------------
__global__ void k_enc(const float* __restrict__ hrelu, const float* __restrict__ w_enc,
                      const float* __restrict__ b_enc, float* __restrict__ latent) {
  __shared__ float hrow[4 * HIDDEN];
  int nb = blockIdx.x * 4;
  int t = threadIdx.x;
#pragma unroll
  for (int j = 0; j < 4; ++j) hrow[j * HIDDEN + t] = hrelu[(size_t)(nb + j) * HIDDEN + t];
  __syncthreads();
  int lat = t & 63;
  int nl = t >> 6;
  float acc = b_enc[lat];
#pragma unroll 8
  for (int k = 0; k < HIDDEN; ++k)
    acc += hrow[nl * HIDDEN + k] * w_enc[k * LATENT + lat];
  latent[(size_t)(nb + nl) * LATENT + lat] = acc;
}

// ------------- decoder L1: hid2 = bf16(relu(latent @ w_d1 + b_d1)) -------------
__global__ void k_dec1(const float* __restrict__ latent, const float* __restrict__ w_d1,
                       const float* __restrict__ b_d1, unsigned short* __restrict__ hid2) {
  __shared__ float lrow[4 * LATENT];
  int nb = blockIdx.x * 4;
  int t = threadIdx.x;
  lrow[t] = latent[(size_t)nb * LATENT + t];  // 4*64 == 256 threads
  __syncthreads();
  float b = b_d1[t];
  float a0 = b, a1 = b, a2 = b, a3 = b;
#pragma unroll 8
  for (int k = 0; k < LATENT; ++k) {
    float wv = w_d1[k * HIDDEN + t];
    a0 += lrow[k] * wv;
    a1 += lrow[LATENT + k] * wv;
    a2 += lrow[2 * LATENT + k] * wv;
    a3 += lrow[3 * LATENT + k] * wv;
  }
  hid2[(size_t)nb * HIDDEN + t]       = f2bf(a0 > 0.f ? a0 : 0.f);
  hid2[(size_t)(nb + 1) * HIDDEN + t] = f2bf(a1 > 0.f ? a1 : 0.f);
  hid2[(size_t)(nb + 2) * HIDDEN + t] = f2bf(a2 > 0.f ? a2 : 0.f);
  hid2[(size_t)(nb + 3) * HIDDEN + t] = f2bf(a3 > 0.f ? a3 : 0.f);
}

// ------------- GEMM3: recon = hid2 @ w_d2 + b_d2 (bf16 MFMA, K=256) -------------
// tile 128x128, K fully staged in LDS, grid (64,157), 512 threads (8 waves 2x4)
__global__ __launch_bounds__(512, 1)
void k_gemm3(const unsigned short* __restrict__ hid2, const unsigned short* __restrict__ wd2t,
             const float* __restrict__ b_d2, float* __restrict__ recon) {
  __shared__ unsigned short Al[128 * 256];
  __shared__ unsigned short Bl[128 * 256];
  const int m0 = blockIdx.x * 128;
  const int n0 = blockIdx.y * 128;
  const int t = threadIdx.x;
  const int lane = t & 63;
  const int wid = t >> 6;
  const int wr = wid >> 2;
  const int wc = wid & 3;
  const int lr = lane & 15;
  const int lg = lane >> 4;

#pragma unroll
  for (int i = 0; i < 8; ++i) {
    int clin = t * 8 + i;      // 0..4095 16B-chunks
    int row = clin >> 5;
    int kc = clin & 31;
    int sl = (kc ^ (row & 7)) * 8;
    *(uint4*)&Al[row * 256 + sl] = *(const uint4*)(hid2 + (size_t)(m0 + row) * 256 + kc * 8);
    *(uint4*)&Bl[row * 256 + sl] = *(const uint4*)(wd2t + (size_t)(n0 + row) * 256 + kc * 8);
  }
  __syncthreads();

  f32x4 acc[4][2];
#pragma unroll
  for (int i = 0; i < 4; ++i) {
    acc[i][0] = (f32x4){0.f, 0.f, 0.f, 0.f};
    acc[i][1] = (f32x4){0.f, 0.f, 0.f, 0.f};
  }

#pragma unroll
  for (int ks = 0; ks < 8; ++ks) {
    short8 a[4], b[2];
#pragma unroll
    for (int mt = 0; mt < 4; ++mt) {
      int m = wr * 64 + mt * 16 + lr;
      int kc = ks * 4 + lg;
      a[mt] = *(const short8*)&Al[m * 256 + ((kc ^ (m & 7)) * 8)];
    }
#pragma unroll
    for (int nt = 0; nt < 2; ++nt) {
      int n = wc * 32 + nt * 16 + lr;
      int kc = ks * 4 + lg;
      b[nt] = *(const short8*)&Bl[n * 256 + ((kc ^ (n & 7)) * 8)];
    }
#pragma unroll
    for (int mt = 0; mt < 4; ++mt)
#pragma unroll
      for (int nt = 0; nt < 2; ++nt)
        acc[mt][nt] = __builtin_amdgcn_mfma_f32_16x16x32_bf16(a[mt], b[nt], acc[mt][nt], 0, 0, 0);
  }

#pragma unroll
  for (int mt = 0; mt < 4; ++mt)
#pragma unroll
    for (int nt = 0; nt < 2; ++nt) {
      int col = n0 + wc * 32 + nt * 16 + lr;
      if (col < IN_DIM) {
        float bias = b_d2[col];
        int rowb = m0 + wr * 64 + mt * 16 + lg * 4;
#pragma unroll
        for (int r = 0; r < 4; ++r)
          recon[(size_t)(rowb + r) * IN_DIM + col] = acc[mt][nt][r] + bias;
      }
    }
}

extern "C" void kernel_launch(void* const* d_in, const int* in_sizes, int n_in,
                              void* d_out, int out_size, void* d_ws, size_t ws_size,
                              hipStream_t stream) {
  const float* x     = (const float*)d_in[0];
  const int*   edge  = (const int*)d_in[1];
  const float* w_gcn = (const float*)d_in[2];
  const float* b_gcn = (const float*)d_in[3];
  const float* w_enc = (const float*)d_in[4];
  const float* b_enc = (const float*)d_in[5];
  const float* w_d1  = (const float*)d_in[6];
  const float* b_d1  = (const float*)d_in[7];
  const float* w_d2  = (const float*)d_in[8];
  const float* b_d2  = (const float*)d_in[9];
  float* out = (float*)d_out;
  (void)in_sizes; (void)n_in; (void)out_size; (void)ws_size;

  char* ws = (char*)d_ws;
  size_t o = 0;
  auto alloc = [&](size_t bytes) {
    char* p = ws + o;
    o += (bytes + 255) & ~(size_t)255;
    return p;
  };
  unsigned short* wpk  = (unsigned short*)alloc((size_t)K_STEPS * HIDDEN * 32 * 2);
  unsigned short* wd2t = (unsigned short*)alloc((size_t)WD2T_ROWS * HIDDEN * 2);
  float* h0p  = (float*)alloc((size_t)2 * N_NODES * HIDDEN * 4);
  float* h0   = (float*)alloc((size_t)N_NODES * HIDDEN * 4);
  float* hrel = (float*)alloc((size_t)N_NODES * HIDDEN * 4);
  unsigned short* hid2 = (unsigned short*)alloc((size_t)N_NODES * HIDDEN * 2);
  int* cnt    = (int*)alloc(N_NODES * 4);
  float* dinv = (float*)alloc(N_NODES * 4);
  int* offs   = (int*)alloc((N_NODES + 1) * 4);
  int* cursor = (int*)alloc(N_NODES * 4);
  int* csr    = (int*)alloc((size_t)N_EDGES * 4);

  const int* erow = edge;
  const int* ecol = edge + N_EDGES;

  hipMemsetAsync(cnt, 0, N_NODES * 4, stream);
  k_count<<<N_EDGES / 256, 256, 0, stream>>>(ecol, cnt);
  k_scan<<<1, 256, 0, stream>>>(cnt, offs, cursor);
  k_dinv<<<N_NODES / 256, 256, 0, stream>>>(cnt, dinv);
  k_fill<<<N_EDGES / 256, 256, 0, stream>>>(erow, ecol, cursor, csr);
  k_pack_wgcn<<<K_STEPS, 256, 0, stream>>>(w_gcn, wpk);
  k_twd2<<<WD2T_ROWS / 64, 256, 0, stream>>>(w_d2, wd2t);
  k_gemm1<<<dim3(N_NODES / 32, 2), 256, 0, stream>>>(x, wpk, h0p);
  k_sum<<<(N_NODES * HIDDEN / 4) / 256, 256, 0, stream>>>(h0p, h0);
  k_agg<<<N_NODES, 256, 0, stream>>>(h0, dinv, offs, csr, b_gcn, hrel);
  float* latent = out + RECON_ELEMS;
  k_enc<<<N_NODES / 4, 256, 0, stream>>>(hrel, w_enc, b_enc, latent);
  k_dec1<<<N_NODES / 4, 256, 0, stream>>>(latent, w_d1, b_d1, hid2);
  k_gemm3<<<dim3(N_NODES / 128, 157), 512, 0, stream>>>(hid2, wd2t, b_d2, out);
}

// Round 2
// 721.101 us; speedup vs baseline: 1.3883x; 1.3883x over previous
//
#include <hip/hip_runtime.h>
#include <stdint.h>

typedef short short8 __attribute__((ext_vector_type(8)));
typedef float f32x4 __attribute__((ext_vector_type(4)));

#define N_NODES 8192
#define IN_DIM 20000
#define HIDDEN 256
#define LATENT 64
#define N_EDGES 262144
#define K_STEPS 625
#define SPLIT0_STEPS 312
#define RECON_ELEMS (8192LL * 20000LL)
#define WD2T_ROWS 20096
#define NSUB3 313   // 64-col subtiles covering 20032 >= 20000 cols

static __device__ __forceinline__ unsigned short f2bf(float f) {
  union { float f; unsigned int u; } v;
  v.f = f;
  unsigned int u = v.u;
  return (unsigned short)((u + 0x7FFFu + ((u >> 16) & 1u)) >> 16);  // RNE
}

// ----------------- graph prep: degree, scan, CSR fill -----------------
__global__ void k_count(const int* __restrict__ col, int* __restrict__ cnt) {
  int e = blockIdx.x * 256 + threadIdx.x;
  if (e < N_EDGES) atomicAdd(&cnt[col[e]], 1);
}

__global__ void k_dinv(const int* __restrict__ cnt, float* __restrict__ dinv) {
  int i = blockIdx.x * 256 + threadIdx.x;
  if (i < N_NODES) dinv[i] = rsqrtf((float)(cnt[i] + 1));  // +1 self loop
}

__global__ void k_scan(const int* __restrict__ cnt, int* __restrict__ offs,
                       int* __restrict__ cursor) {
  __shared__ int ps[256];
  int t = threadIdx.x;
  int local[32];
  int s = 0;
#pragma unroll
  for (int i = 0; i < 32; ++i) { local[i] = cnt[t * 32 + i]; s += local[i]; }
  ps[t] = s;
  __syncthreads();
  for (int d = 1; d < 256; d <<= 1) {
    int v = (t >= d) ? ps[t - d] : 0;
    __syncthreads();
    ps[t] += v;
    __syncthreads();
  }
  int pre = (t == 0) ? 0 : ps[t - 1];
#pragma unroll
  for (int i = 0; i < 32; ++i) {
    offs[t * 32 + i] = pre;
    cursor[t * 32 + i] = pre;
    pre += local[i];
  }
  if (t == 255) offs[N_NODES] = pre;
}

__global__ void k_fill(const int* __restrict__ row, const int* __restrict__ col,
                       int* __restrict__ cursor, int* __restrict__ csr_src) {
  int e = blockIdx.x * 256 + threadIdx.x;
  if (e < N_EDGES) {
    int c = col[e];
    int pos = atomicAdd(&cursor[c], 1);
    csr_src[pos] = row[e];
  }
}

// ------- pack w_gcn [20000][256] f32 -> tiles [kstep][n=256][k=32] bf16 -------
__global__ void k_pack_wgcn(const float* __restrict__ w, unsigned short* __restrict__ pk) {
  int s = blockIdx.x;   // 625 k-steps
  int t = threadIdx.x;  // n = t
  int k0 = s * 32;
  unsigned int packed[16];
#pragma unroll
  for (int j = 0; j < 16; ++j) {
    float a = w[(size_t)(k0 + 2 * j) * HIDDEN + t];
    float b = w[(size_t)(k0 + 2 * j + 1) * HIDDEN + t];
    packed[j] = (unsigned)f2bf(a) | ((unsigned)f2bf(b) << 16);
  }
  uint4* dst = (uint4*)(pk + ((size_t)s * HIDDEN + t) * 32);
#pragma unroll
  for (int j = 0; j < 4; ++j)
    dst[j] = make_uint4(packed[4 * j], packed[4 * j + 1], packed[4 * j + 2], packed[4 * j + 3]);
}

// ------- transpose w_d2 [256][20000] f32 -> [20096][256] bf16, zero-padded,
// ------- with 16B-chunk XOR swizzle (chunk c -> c ^ (row&7)) baked in  -------
__global__ void k_twd2(const float* __restrict__ wd2, unsigned short* __restrict__ wd2t) {
  __shared__ float tile[HIDDEN * 64];  // [k][n_local], 64 KB
  int n0 = blockIdx.x * 64;            // 314 blocks
  int t = threadIdx.x;
  int tk = t >> 6;   // 0..3
  int tn = t & 63;
#pragma unroll 4
  for (int kb = 0; kb < 64; ++kb) {
    int k = kb * 4 + tk;
    int n = n0 + tn;
    tile[k * 64 + tn] = (n < IN_DIM) ? wd2[(size_t)k * IN_DIM + n] : 0.0f;
  }
  __syncthreads();
  int rl = t >> 2;   // out row local 0..63
  int q = t & 3;     // k quarter
  unsigned int packed[32];
#pragma unroll
  for (int j = 0; j < 32; ++j) {
    float a = tile[(q * 64 + 2 * j) * 64 + rl];
    float b = tile[(q * 64 + 2 * j + 1) * 64 + rl];
    packed[j] = (unsigned)f2bf(a) | ((unsigned)f2bf(b) << 16);
  }
  int rs = rl & 7;   // (n0+rl)&7 == rl&7 since n0 % 64 == 0
  uint4* dst = (uint4*)(wd2t + (size_t)(n0 + rl) * HIDDEN + q * 64);
#pragma unroll
  for (int j = 0; j < 8; ++j)
    dst[j ^ rs] = make_uint4(packed[4 * j], packed[4 * j + 1], packed[4 * j + 2], packed[4 * j + 3]);
}

// ----------------- GEMM1: h0p[split] = x @ w_gcn (bf16 MFMA) -----------------
__global__ __launch_bounds__(256, 2)
void k_gemm1(const float* __restrict__ x, const unsigned short* __restrict__ wpk,
             float* __restrict__ h0p) {
  const int m0 = blockIdx.x * 32;
  const int split = blockIdx.y;
  const int s_beg = split ? SPLIT0_STEPS : 0;
  const int s_end = split ? K_STEPS : SPLIT0_STEPS;

  const int t = threadIdx.x;
  const int lane = t & 63;
  const int w = t >> 6;
  const int lr = lane & 15;
  const int lg = lane >> 4;

  __shared__ unsigned short Alds[2][32 * 40];
  __shared__ unsigned short Blds[2][256 * 32];

  const int arow = t >> 3;
  const int ak = (t & 7) * 4;
  const float* xrow = x + (size_t)(m0 + arow) * IN_DIM + ak;
  const int bsw = ((t ^ (t >> 2)) & 3);

  f32x4 acc[2][4];
#pragma unroll
  for (int i = 0; i < 2; ++i)
#pragma unroll
    for (int j = 0; j < 4; ++j) acc[i][j] = (f32x4){0.f, 0.f, 0.f, 0.f};

  float4 areg;
  uint4 breg0, breg1, breg2, breg3;

  areg = *(const float4*)(xrow + (size_t)s_beg * 32);
  {
    const uint4* bp = (const uint4*)(wpk + ((size_t)s_beg * 256 + t) * 32);
    breg0 = bp[0]; breg1 = bp[1]; breg2 = bp[2]; breg3 = bp[3];
  }
  {
    uint2 ap;
    ap.x = (unsigned)f2bf(areg.x) | ((unsigned)f2bf(areg.y) << 16);
    ap.y = (unsigned)f2bf(areg.z) | ((unsigned)f2bf(areg.w) << 16);
    *(uint2*)&Alds[0][arow * 40 + ak] = ap;
    uint4* br = (uint4*)&Blds[0][t * 32];
    br[0 ^ bsw] = breg0; br[1 ^ bsw] = breg1; br[2 ^ bsw] = breg2; br[3 ^ bsw] = breg3;
  }
  __syncthreads();

  int cur = 0;
  for (int s = s_beg; s < s_end; ++s) {
    bool more = (s + 1 < s_end);
    if (more) {
      areg = *(const float4*)(xrow + (size_t)(s + 1) * 32);
      const uint4* bp = (const uint4*)(wpk + ((size_t)(s + 1) * 256 + t) * 32);
      breg0 = bp[0]; breg1 = bp[1]; breg2 = bp[2]; breg3 = bp[3];
    }
    {
      short8 a0 = *(const short8*)&Alds[cur][lr * 40 + lg * 8];
      short8 a1 = *(const short8*)&Alds[cur][(16 + lr) * 40 + lg * 8];
#pragma unroll
      for (int ct = 0; ct < 4; ++ct) {
        int n = w * 64 + ct * 16 + lr;
        int sw = ((n ^ (n >> 2)) & 3);
        short8 b = *(const short8*)&Blds[cur][n * 32 + ((lg ^ sw) * 8)];
        acc[0][ct] = __builtin_amdgcn_mfma_f32_16x16x32_bf16(a0, b, acc[0][ct], 0, 0, 0);
        acc[1][ct] = __builtin_amdgcn_mfma_f32_16x16x32_bf16(a1, b, acc[1][ct], 0, 0, 0);
      }
    }
    if (more) {
      __syncthreads();
      int nb = cur ^ 1;
      uint2 ap;
      ap.x = (unsigned)f2bf(areg.x) | ((unsigned)f2bf(areg.y) << 16);
      ap.y = (unsigned)f2bf(areg.z) | ((unsigned)f2bf(areg.w) << 16);
      *(uint2*)&Alds[nb][arow * 40 + ak] = ap;
      uint4* br = (uint4*)&Blds[nb][t * 32];
      br[0 ^ bsw] = breg0; br[1 ^ bsw] = breg1; br[2 ^ bsw] = breg2; br[3 ^ bsw] = breg3;
      __syncthreads();
      cur = nb;
    }
  }

  float* outp = h0p + (size_t)split * (N_NODES * HIDDEN) + (size_t)m0 * HIDDEN;
#pragma unroll
  for (int mt = 0; mt < 2; ++mt)
#pragma unroll
    for (int ct = 0; ct < 4; ++ct) {
      int col = w * 64 + ct * 16 + lr;
#pragma unroll
      for (int r = 0; r < 4; ++r) {
        int rowi = mt * 16 + lg * 4 + r;
        outp[rowi * HIDDEN + col] = acc[mt][ct][r];
      }
    }
}

__global__ void k_sum(const float* __restrict__ p, float* __restrict__ h0) {
  int i = blockIdx.x * 256 + threadIdx.x;
  float4 a = ((const float4*)p)[i];
  float4 b = ((const float4*)p)[i + (N_NODES * HIDDEN / 4)];
  float4 r;
  r.x = a.x + b.x; r.y = a.y + b.y; r.z = a.z + b.z; r.w = a.w + b.w;
  ((float4*)h0)[i] = r;
}

// ------------- GCN aggregate (CSR gather) + bias + relu -------------
__global__ void k_agg(const float* __restrict__ h0, const float* __restrict__ dinv,
                      const int* __restrict__ offs, const int* __restrict__ csr_src,
                      const float* __restrict__ bias, float* __restrict__ hrelu) {
  int c = blockIdx.x;
  int t = threadIdx.x;
  float dc = dinv[c];
  float acc = h0[(size_t)c * HIDDEN + t] * dc * dc;  // self loop
  int beg = offs[c], end = offs[c + 1];
  for (int i = beg; i < end; ++i) {
    int r = csr_src[i];
    float wgt = dinv[r] * dc;
    acc += h0[(size_t)r * HIDDEN + t] * wgt;
  }
  float v = acc + bias[t];
  hrelu[(size_t)c * HIDDEN + t] = v > 0.f ? v : 0.f;
}

// ------------- encoder: latent = relu_h @ w_enc + b_enc (fp32) -------------
__global__ void k_enc(const float* __restrict__ hrelu, const float* __restrict__ w_enc,
                      const float* __restrict__ b_enc, float* __restrict__ latent) {
  __shared__ float hrow[4 * HIDDEN];
  int nb = blockIdx.x * 4;
  int t = threadIdx.x;
#pragma unroll
  for (int j = 0; j < 4; ++j) hrow[j * HIDDEN + t] = hrelu[(size_t)(nb + j) * HIDDEN + t];
  __syncthreads();
  int lat = t & 63;
  int nl = t >> 6;
  float acc = b_enc[lat];
#pragma unroll 8
  for (int k = 0; k < HIDDEN; ++k)
    acc += hrow[nl * HIDDEN + k] * w_enc[k * LATENT + lat];
  latent[(size_t)(nb + nl) * LATENT + lat] = acc;
}

// ------------- decoder L1: hid2 = bf16(relu(latent @ w_d1 + b_d1)) -------------
__global__ void k_dec1(const float* __restrict__ latent, const float* __restrict__ w_d1,
                       const float* __restrict__ b_d1, unsigned short* __restrict__ hid2) {
  __shared__ float lrow[4 * LATENT];
  int nb = blockIdx.x * 4;
  int t = threadIdx.x;
  lrow[t] = latent[(size_t)nb * LATENT + t];  // 4*64 == 256 threads
  __syncthreads();
  float b = b_d1[t];
  float a0 = b, a1 = b, a2 = b, a3 = b;
#pragma unroll 8
  for (int k = 0; k < LATENT; ++k) {
    float wv = w_d1[k * HIDDEN + t];
    a0 += lrow[k] * wv;
    a1 += lrow[LATENT + k] * wv;
    a2 += lrow[2 * LATENT + k] * wv;
    a3 += lrow[3 * LATENT + k] * wv;
  }
  hid2[(size_t)nb * HIDDEN + t]       = f2bf(a0 > 0.f ? a0 : 0.f);
  hid2[(size_t)(nb + 1) * HIDDEN + t] = f2bf(a1 > 0.f ? a1 : 0.f);
  hid2[(size_t)(nb + 2) * HIDDEN + t] = f2bf(a2 > 0.f ? a2 : 0.f);
  hid2[(size_t)(nb + 3) * HIDDEN + t] = f2bf(a3 > 0.f ? a3 : 0.f);
}

// ------------- GEMM3: recon = hid2 @ w_d2 + b_d2 (bf16 MFMA, K=256) -------------
// Persistent m-panel (128 rows) streaming over 64-col subtiles.
// A in registers (16 x short8/lane), B double-buffered LDS via global_load_lds
// (swizzle baked in wd2t), LDS-transpose epilogue -> float4 stores, 128B segments.
// grid (64, 8), 512 threads (8 waves as 4m x 2n), LDS 80KB -> 2 blocks/CU.
__global__ __launch_bounds__(512, 4)
void k_gemm3(const unsigned short* __restrict__ hid2, const unsigned short* __restrict__ wd2t,
             const float* __restrict__ b_d2, float* __restrict__ recon) {
  __shared__ unsigned short Bl[2][64 * 256];  // 2 x 32KB, chunk-XOR swizzled
  __shared__ float TB[8 * 512];               // per-wave 16x32 transpose buf, 16KB
  const int t = threadIdx.x;
  const int lane = t & 63;
  const int wid = t >> 6;
  const int wm = wid >> 1;   // 0..3: m-group of 32 rows
  const int wn = wid & 1;    // 0..1: n-group of 32 cols
  const int lr = lane & 15;
  const int lg = lane >> 4;
  const int m0 = blockIdx.x * 128;
  const int chunk = blockIdx.y;
  const int s0 = (NSUB3 * chunk) >> 3;
  const int s1 = (NSUB3 * (chunk + 1)) >> 3;

  // ---- A preload into registers: wave's 32 rows x K=256 ----
  short8 a[2][8];
#pragma unroll
  for (int mt = 0; mt < 2; ++mt)
#pragma unroll
    for (int ks = 0; ks < 8; ++ks)
      a[mt][ks] = *(const short8*)(hid2 + (size_t)(m0 + wm * 32 + mt * 16 + lr) * 256 + ks * 32 + lg * 8);

  auto stage = [&](int sub, int buf) {
#pragma unroll
    for (int i = 0; i < 4; ++i) {
      const unsigned short* g = wd2t + (size_t)sub * (64 * 256) + ((wid * 4 + i) * 512 + lane * 8);
      unsigned short* l = &Bl[buf][(wid * 4 + i) * 512];
      __builtin_amdgcn_global_load_lds(
          (const __attribute__((address_space(1))) unsigned int*)g,
          (__attribute__((address_space(3))) unsigned int*)l, 16, 0, 0);
    }
  };

  stage(s0, 0);
  __syncthreads();

  int cur = 0;
  for (int sub = s0; sub < s1; ++sub) {
    if (sub + 1 < s1) stage(sub + 1, cur ^ 1);

    f32x4 acc[2][2];
#pragma unroll
    for (int i = 0; i < 2; ++i)
#pragma unroll
      for (int j = 0; j < 2; ++j) acc[i][j] = (f32x4){0.f, 0.f, 0.f, 0.f};

    const int rl0 = wn * 32 + lr;
    const int rl1 = rl0 + 16;
#pragma unroll
    for (int ks = 0; ks < 8; ++ks) {
      short8 b0 = *(const short8*)&Bl[cur][rl0 * 256 + (((ks * 4 + lg) ^ (lr & 7)) << 3)];
      short8 b1 = *(const short8*)&Bl[cur][rl1 * 256 + (((ks * 4 + lg) ^ (lr & 7)) << 3)];
      acc[0][0] = __builtin_amdgcn_mfma_f32_16x16x32_bf16(a[0][ks], b0, acc[0][0], 0, 0, 0);
      acc[1][0] = __builtin_amdgcn_mfma_f32_16x16x32_bf16(a[1][ks], b0, acc[1][0], 0, 0, 0);
      acc[0][1] = __builtin_amdgcn_mfma_f32_16x16x32_bf16(a[0][ks], b1, acc[0][1], 0, 0, 0);
      acc[1][1] = __builtin_amdgcn_mfma_f32_16x16x32_bf16(a[1][ks], b1, acc[1][1], 0, 0, 0);
    }

    // ---- epilogue: per-wave LDS transpose -> coalesced float4 stores ----
    const int cg = (lane & 7) * 4;
    const int gc = sub * 64 + wn * 32 + cg;
    f32x4 bias4 = (f32x4){0.f, 0.f, 0.f, 0.f};
    if (gc < IN_DIM) bias4 = *(const f32x4*)&b_d2[gc];
    float* TBw = TB + wid * 512;
#pragma unroll
    for (int mt = 0; mt < 2; ++mt) {
#pragma unroll
      for (int nt = 0; nt < 2; ++nt)
#pragma unroll
        for (int r = 0; r < 4; ++r) {
          int row = lg * 4 + r;
          TBw[row * 32 + ((nt * 16 + lr) ^ (((row >> 2) & 1) << 4))] = acc[mt][nt][r];
        }
#pragma unroll
      for (int p = 0; p < 2; ++p) {
        int row = p * 8 + (lane >> 3);
        f32x4 v = *(const f32x4*)&TBw[row * 32 + (cg ^ (((row >> 2) & 1) << 4))];
        if (gc < IN_DIM) {
          int gr = m0 + wm * 32 + mt * 16 + row;
          *(f32x4*)&recon[(size_t)gr * IN_DIM + gc] = v + bias4;
        }
      }
    }
    __syncthreads();
    cur ^= 1;
  }
}

extern "C" void kernel_launch(void* const* d_in, const int* in_sizes, int n_in,
                              void* d_out, int out_size, void* d_ws, size_t ws_size,
                              hipStream_t stream) {
  const float* x     = (const float*)d_in[0];
  const int*   edge  = (const int*)d_in[1];
  const float* w_gcn = (const float*)d_in[2];
  const float* b_gcn = (const float*)d_in[3];
  const float* w_enc = (const float*)d_in[4];
  const float* b_enc = (const float*)d_in[5];
  const float* w_d1  = (const float*)d_in[6];
  const float* b_d1  = (const float*)d_in[7];
  const float* w_d2  = (const float*)d_in[8];
  const float* b_d2  = (const float*)d_in[9];
  float* out = (float*)d_out;
  (void)in_sizes; (void)n_in; (void)out_size; (void)ws_size;

  char* ws = (char*)d_ws;
  size_t o = 0;
  auto alloc = [&](size_t bytes) {
    char* p = ws + o;
    o += (bytes + 255) & ~(size_t)255;
    return p;
  };
  unsigned short* wpk  = (unsigned short*)alloc((size_t)K_STEPS * HIDDEN * 32 * 2);
  unsigned short* wd2t = (unsigned short*)alloc((size_t)WD2T_ROWS * HIDDEN * 2);
  float* h0p  = (float*)alloc((size_t)2 * N_NODES * HIDDEN * 4);
  float* h0   = (float*)alloc((size_t)N_NODES * HIDDEN * 4);
  float* hrel = (float*)alloc((size_t)N_NODES * HIDDEN * 4);
  unsigned short* hid2 = (unsigned short*)alloc((size_t)N_NODES * HIDDEN * 2);
  int* cnt    = (int*)alloc(N_NODES * 4);
  float* dinv = (float*)alloc(N_NODES * 4);
  int* offs   = (int*)alloc((N_NODES + 1) * 4);
  int* cursor = (int*)alloc(N_NODES * 4);
  int* csr    = (int*)alloc((size_t)N_EDGES * 4);

  const int* erow = edge;
  const int* ecol = edge + N_EDGES;

  hipMemsetAsync(cnt, 0, N_NODES * 4, stream);
  k_count<<<N_EDGES / 256, 256, 0, stream>>>(ecol, cnt);
  k_scan<<<1, 256, 0, stream>>>(cnt, offs, cursor);
  k_dinv<<<N_NODES / 256, 256, 0, stream>>>(cnt, dinv);
  k_fill<<<N_EDGES / 256, 256, 0, stream>>>(erow, ecol, cursor, csr);
  k_pack_wgcn<<<K_STEPS, 256, 0, stream>>>(w_gcn, wpk);
  k_twd2<<<WD2T_ROWS / 64, 256, 0, stream>>>(w_d2, wd2t);
  k_gemm1<<<dim3(N_NODES / 32, 2), 256, 0, stream>>>(x, wpk, h0p);
  k_sum<<<(N_NODES * HIDDEN / 4) / 256, 256, 0, stream>>>(h0p, h0);
  k_agg<<<N_NODES, 256, 0, stream>>>(h0, dinv, offs, csr, b_gcn, hrel);
  float* latent = out + RECON_ELEMS;
  k_enc<<<N_NODES / 4, 256, 0, stream>>>(hrel, w_enc, b_enc, latent);
  k_dec1<<<N_NODES / 4, 256, 0, stream>>>(latent, w_d1, b_d1, hid2);
  k_gemm3<<<dim3(N_NODES / 128, 8), 512, 0, stream>>>(hid2, wd2t, b_d2, out);
}

// Round 3
// 630.076 us; speedup vs baseline: 1.5888x; 1.1445x over previous
//
#include <hip/hip_runtime.h>
#include <stdint.h>

typedef short short8 __attribute__((ext_vector_type(8)));
typedef float f32x4 __attribute__((ext_vector_type(4)));

#define N_NODES 8192
#define IN_DIM 20000
#define HIDDEN 256
#define LATENT 64
#define N_EDGES 262144
#define K_STEPS 625
#define RECON_ELEMS (8192LL * 20000LL)
#define WD2T_ROWS 20096
#define NSUB3 313   // 64-col subtiles covering 20032 >= 20000 cols

static __device__ __forceinline__ unsigned short f2bf(float f) {
  union { float f; unsigned int u; } v;
  v.f = f;
  unsigned int u = v.u;
  return (unsigned short)((u + 0x7FFFu + ((u >> 16) & 1u)) >> 16);  // RNE
}

// ----------------- graph prep: degree, scan, CSR fill -----------------
__global__ void k_count(const int* __restrict__ col, int* __restrict__ cnt) {
  int e = blockIdx.x * 256 + threadIdx.x;
  if (e < N_EDGES) atomicAdd(&cnt[col[e]], 1);
}

__global__ void k_dinv(const int* __restrict__ cnt, float* __restrict__ dinv) {
  int i = blockIdx.x * 256 + threadIdx.x;
  if (i < N_NODES) dinv[i] = rsqrtf((float)(cnt[i] + 1));  // +1 self loop
}

__global__ void k_scan(const int* __restrict__ cnt, int* __restrict__ offs,
                       int* __restrict__ cursor) {
  __shared__ int ps[256];
  int t = threadIdx.x;
  int local[32];
  int s = 0;
#pragma unroll
  for (int i = 0; i < 32; ++i) { local[i] = cnt[t * 32 + i]; s += local[i]; }
  ps[t] = s;
  __syncthreads();
  for (int d = 1; d < 256; d <<= 1) {
    int v = (t >= d) ? ps[t - d] : 0;
    __syncthreads();
    ps[t] += v;
    __syncthreads();
  }
  int pre = (t == 0) ? 0 : ps[t - 1];
#pragma unroll
  for (int i = 0; i < 32; ++i) {
    offs[t * 32 + i] = pre;
    cursor[t * 32 + i] = pre;
    pre += local[i];
  }
  if (t == 255) offs[N_NODES] = pre;
}

__global__ void k_fill(const int* __restrict__ row, const int* __restrict__ col,
                       int* __restrict__ cursor, int* __restrict__ csr_src) {
  int e = blockIdx.x * 256 + threadIdx.x;
  if (e < N_EDGES) {
    int c = col[e];
    int pos = atomicAdd(&cursor[c], 1);
    csr_src[pos] = row[e];
  }
}

// ------- pack w_gcn [20000][256] f32 -> tiles [kstep][n=256][k=32] bf16,
// ------- 16B-chunk XOR (j ^ ((n>>1)&3)) baked for conflict-free LDS reads ----
__global__ void k_pack_wgcn(const float* __restrict__ w, unsigned short* __restrict__ pk) {
  int s = blockIdx.x;   // 625 k-steps
  int t = threadIdx.x;  // n = t
  int k0 = s * 32;
  unsigned int packed[16];
#pragma unroll
  for (int j = 0; j < 16; ++j) {
    float a = w[(size_t)(k0 + 2 * j) * HIDDEN + t];
    float b = w[(size_t)(k0 + 2 * j + 1) * HIDDEN + t];
    packed[j] = (unsigned)f2bf(a) | ((unsigned)f2bf(b) << 16);
  }
  int sw = (t >> 1) & 3;
  uint4* dst = (uint4*)(pk + ((size_t)s * HIDDEN + t) * 32);
#pragma unroll
  for (int j = 0; j < 4; ++j)
    dst[j ^ sw] = make_uint4(packed[4 * j], packed[4 * j + 1], packed[4 * j + 2], packed[4 * j + 3]);
}

// ------- transpose w_d2 [256][20000] f32 -> [20096][256] bf16, zero-padded,
// ------- with 16B-chunk XOR swizzle (chunk c -> c ^ (row&7)) baked in  -------
__global__ void k_twd2(const float* __restrict__ wd2, unsigned short* __restrict__ wd2t) {
  __shared__ float tile[HIDDEN * 64];  // [k][n_local], 64 KB
  int n0 = blockIdx.x * 64;            // 314 blocks
  int t = threadIdx.x;
  int tk = t >> 6;   // 0..3
  int tn = t & 63;
#pragma unroll 4
  for (int kb = 0; kb < 64; ++kb) {
    int k = kb * 4 + tk;
    int n = n0 + tn;
    tile[k * 64 + tn] = (n < IN_DIM) ? wd2[(size_t)k * IN_DIM + n] : 0.0f;
  }
  __syncthreads();
  int rl = t >> 2;   // out row local 0..63
  int q = t & 3;     // k quarter
  unsigned int packed[32];
#pragma unroll
  for (int j = 0; j < 32; ++j) {
    float a = tile[(q * 64 + 2 * j) * 64 + rl];
    float b = tile[(q * 64 + 2 * j + 1) * 64 + rl];
    packed[j] = (unsigned)f2bf(a) | ((unsigned)f2bf(b) << 16);
  }
  int rs = rl & 7;   // (n0+rl)&7 == rl&7 since n0 % 64 == 0
  uint4* dst = (uint4*)(wd2t + (size_t)(n0 + rl) * HIDDEN + q * 64);
#pragma unroll
  for (int j = 0; j < 8; ++j)
    dst[j ^ rs] = make_uint4(packed[4 * j], packed[4 * j + 1], packed[4 * j + 2], packed[4 * j + 3]);
}

// ----------------- GEMM1: h0p[split] = x @ w_gcn (bf16 MFMA) -----------------
// tile 64x256, BK=32, split-K=4, grid (128,4), 512 thr (8 waves 2m x 4n),
// B via global_load_lds (XOR pre-baked in wpk), A reg-staged issue-early.
__global__ __launch_bounds__(512, 4)
void k_gemm1(const float* __restrict__ x, const unsigned short* __restrict__ wpk,
             float* __restrict__ h0p) {
  const int m0 = blockIdx.x * 64;
  const int split = blockIdx.y;
  const int s_beg = (K_STEPS * split) >> 2;
  const int s_end = (K_STEPS * (split + 1)) >> 2;

  const int t = threadIdx.x;
  const int lane = t & 63;
  const int wid = t >> 6;
  const int wm = wid >> 2;   // 0..1: 32-row group
  const int wn = wid & 3;    // 0..3: 64-col group
  const int lr = lane & 15;
  const int lg = lane >> 4;

  __shared__ unsigned short Alds[2][64 * 40];   // pad 40: 2-way = free
  __shared__ unsigned short Blds[2][256 * 32];  // linear copy of pre-swizzled wpk

  const int arow = t >> 3;       // 0..63
  const int ak = (t & 7) * 4;    // 0..28
  const float* xrow = x + (size_t)(m0 + arow) * IN_DIM + ak;

  f32x4 acc[2][4];
#pragma unroll
  for (int i = 0; i < 2; ++i)
#pragma unroll
    for (int j = 0; j < 4; ++j) acc[i][j] = (f32x4){0.f, 0.f, 0.f, 0.f};

  auto stageB = [&](int s, int buf) {
    const unsigned short* g = wpk + (size_t)s * (HIDDEN * 32) + wid * 512 + lane * 8;
    __builtin_amdgcn_global_load_lds(
        (const __attribute__((address_space(1))) unsigned int*)g,
        (__attribute__((address_space(3))) unsigned int*)&Blds[buf][wid * 512], 16, 0, 0);
    __builtin_amdgcn_global_load_lds(
        (const __attribute__((address_space(1))) unsigned int*)(g + 4096),
        (__attribute__((address_space(3))) unsigned int*)&Blds[buf][4096 + wid * 512], 16, 0, 0);
  };

  float4 areg = *(const float4*)(xrow + (size_t)s_beg * 32);
  stageB(s_beg, 0);
  {
    uint2 ap;
    ap.x = (unsigned)f2bf(areg.x) | ((unsigned)f2bf(areg.y) << 16);
    ap.y = (unsigned)f2bf(areg.z) | ((unsigned)f2bf(areg.w) << 16);
    *(uint2*)&Alds[0][arow * 40 + ak] = ap;
  }
  __syncthreads();  // drains glds (vmcnt) + A writes (lgkm)

  int cur = 0;
  for (int s = s_beg; s < s_end; ++s) {
    const bool more = (s + 1 < s_end);
    if (more) {
      areg = *(const float4*)(xrow + (size_t)(s + 1) * 32);  // issue early
      stageB(s + 1, cur ^ 1);                                 // async into other buf
    }
    {
      short8 a0 = *(const short8*)&Alds[cur][(wm * 32 + lr) * 40 + lg * 8];
      short8 a1 = *(const short8*)&Alds[cur][(wm * 32 + 16 + lr) * 40 + lg * 8];
#pragma unroll
      for (int nt = 0; nt < 4; ++nt) {
        int n = wn * 64 + nt * 16 + lr;
        short8 b = *(const short8*)&Blds[cur][n * 32 + ((lg ^ ((n >> 1) & 3)) * 8)];
        acc[0][nt] = __builtin_amdgcn_mfma_f32_16x16x32_bf16(a0, b, acc[0][nt], 0, 0, 0);
        acc[1][nt] = __builtin_amdgcn_mfma_f32_16x16x32_bf16(a1, b, acc[1][nt], 0, 0, 0);
      }
    }
    __syncthreads();  // reads of cur done; glds(nb) drained
    if (more) {
      uint2 ap;
      ap.x = (unsigned)f2bf(areg.x) | ((unsigned)f2bf(areg.y) << 16);
      ap.y = (unsigned)f2bf(areg.z) | ((unsigned)f2bf(areg.w) << 16);
      *(uint2*)&Alds[cur ^ 1][arow * 40 + ak] = ap;
      __syncthreads();  // A(nb) visible
    }
    cur ^= 1;
  }

  float* outp = h0p + (size_t)split * (N_NODES * HIDDEN) + (size_t)m0 * HIDDEN;
#pragma unroll
  for (int mt = 0; mt < 2; ++mt)
#pragma unroll
    for (int nt = 0; nt < 4; ++nt) {
      int col = wn * 64 + nt * 16 + lr;
#pragma unroll
      for (int r = 0; r < 4; ++r) {
        int rowi = wm * 32 + mt * 16 + lg * 4 + r;
        outp[rowi * HIDDEN + col] = acc[mt][nt][r];
      }
    }
}

__global__ void k_sum(const float* __restrict__ p, float* __restrict__ h0) {
  int i = blockIdx.x * 256 + threadIdx.x;
  float4 a = ((const float4*)p)[i];
  float4 b = ((const float4*)p)[i + (N_NODES * HIDDEN / 4)];
  float4 c = ((const float4*)p)[i + 2 * (N_NODES * HIDDEN / 4)];
  float4 d = ((const float4*)p)[i + 3 * (N_NODES * HIDDEN / 4)];
  float4 r;
  r.x = (a.x + b.x) + (c.x + d.x);
  r.y = (a.y + b.y) + (c.y + d.y);
  r.z = (a.z + b.z) + (c.z + d.z);
  r.w = (a.w + b.w) + (c.w + d.w);
  ((float4*)h0)[i] = r;
}

// ------------- GCN aggregate (CSR gather) + bias + relu -------------
__global__ void k_agg(const float* __restrict__ h0, const float* __restrict__ dinv,
                      const int* __restrict__ offs, const int* __restrict__ csr_src,
                      const float* __restrict__ bias, float* __restrict__ hrelu) {
  int c = blockIdx.x;
  int t = threadIdx.x;
  float dc = dinv[c];
  float acc = h0[(size_t)c * HIDDEN + t] * dc * dc;  // self loop
  int beg = offs[c], end = offs[c + 1];
  for (int i = beg; i < end; ++i) {
    int r = csr_src[i];
    float wgt = dinv[r] * dc;
    acc += h0[(size_t)r * HIDDEN + t] * wgt;
  }
  float v = acc + bias[t];
  hrelu[(size_t)c * HIDDEN + t] = v > 0.f ? v : 0.f;
}

// ------------- encoder: latent = relu_h @ w_enc + b_enc (fp32) -------------
__global__ void k_enc(const float* __restrict__ hrelu, const float* __restrict__ w_enc,
                      const float* __restrict__ b_enc, float* __restrict__ latent) {
  __shared__ float hrow[4 * HIDDEN];
  int nb = blockIdx.x * 4;
  int t = threadIdx.x;
#pragma unroll
  for (int j = 0; j < 4; ++j) hrow[j * HIDDEN + t] = hrelu[(size_t)(nb + j) * HIDDEN + t];
  __syncthreads();
  int lat = t & 63;
  int nl = t >> 6;
  float acc = b_enc[lat];
#pragma unroll 8
  for (int k = 0; k < HIDDEN; ++k)
    acc += hrow[nl * HIDDEN + k] * w_enc[k * LATENT + lat];
  latent[(size_t)(nb + nl) * LATENT + lat] = acc;
}

// ------------- decoder L1: hid2 = bf16(relu(latent @ w_d1 + b_d1)) -------------
__global__ void k_dec1(const float* __restrict__ latent, const float* __restrict__ w_d1,
                       const float* __restrict__ b_d1, unsigned short* __restrict__ hid2) {
  __shared__ float lrow[4 * LATENT];
  int nb = blockIdx.x * 4;
  int t = threadIdx.x;
  lrow[t] = latent[(size_t)nb * LATENT + t];  // 4*64 == 256 threads
  __syncthreads();
  float b = b_d1[t];
  float a0 = b, a1 = b, a2 = b, a3 = b;
#pragma unroll 8
  for (int k = 0; k < LATENT; ++k) {
    float wv = w_d1[k * HIDDEN + t];
    a0 += lrow[k] * wv;
    a1 += lrow[LATENT + k] * wv;
    a2 += lrow[2 * LATENT + k] * wv;
    a3 += lrow[3 * LATENT + k] * wv;
  }
  hid2[(size_t)nb * HIDDEN + t]       = f2bf(a0 > 0.f ? a0 : 0.f);
  hid2[(size_t)(nb + 1) * HIDDEN + t] = f2bf(a1 > 0.f ? a1 : 0.f);
  hid2[(size_t)(nb + 2) * HIDDEN + t] = f2bf(a2 > 0.f ? a2 : 0.f);
  hid2[(size_t)(nb + 3) * HIDDEN + t] = f2bf(a3 > 0.f ? a3 : 0.f);
}

// ------------- GEMM3: recon = hid2 @ w_d2 + b_d2 (bf16 MFMA, K=256) -------------
// Persistent m-panel (128 rows), 4 waves (2m x 2n), wave = 64r x 32c,
// A fully in registers (32 x short8), B dbuf LDS via glds (pre-swizzled wd2t),
// per-wave LDS-transpose epilogue -> 128B-segment float4 stores.
// grid (64, 8), 256 threads, LDS 72KB -> 2 blocks/CU.
__global__ __launch_bounds__(256, 2)
void k_gemm3(const unsigned short* __restrict__ hid2, const unsigned short* __restrict__ wd2t,
             const float* __restrict__ b_d2, float* __restrict__ recon) {
  __shared__ unsigned short Bl[2][64 * 256];  // 2 x 32KB, chunk-XOR swizzled
  __shared__ float TB[4 * 512];               // per-wave 16x32 transpose buf, 8KB
  const int t = threadIdx.x;
  const int lane = t & 63;
  const int wid = t >> 6;
  const int wm = wid >> 1;   // 0..1: m-group of 64 rows
  const int wn = wid & 1;    // 0..1: n-group of 32 cols
  const int lr = lane & 15;
  const int lg = lane >> 4;
  const int m0 = blockIdx.x * 128;
  const int chunk = blockIdx.y;
  const int s0 = (NSUB3 * chunk) >> 3;
  const int s1 = (NSUB3 * (chunk + 1)) >> 3;

  // ---- A preload into registers: wave's 64 rows x K=256 (128 VGPR) ----
  short8 a[4][8];
#pragma unroll
  for (int mt = 0; mt < 4; ++mt)
#pragma unroll
    for (int ks = 0; ks < 8; ++ks)
      a[mt][ks] = *(const short8*)(hid2 + (size_t)(m0 + wm * 64 + mt * 16 + lr) * 256 + ks * 32 + lg * 8);

  auto stage = [&](int sub, int buf) {
#pragma unroll
    for (int i = 0; i < 8; ++i) {
      const unsigned short* g = wd2t + (size_t)sub * (64 * 256) + ((wid * 8 + i) * 512 + lane * 8);
      unsigned short* l = &Bl[buf][(wid * 8 + i) * 512];
      __builtin_amdgcn_global_load_lds(
          (const __attribute__((address_space(1))) unsigned int*)g,
          (__attribute__((address_space(3))) unsigned int*)l, 16, 0, 0);
    }
  };

  stage(s0, 0);
  __syncthreads();

  int cur = 0;
  for (int sub = s0; sub < s1; ++sub) {
    if (sub + 1 < s1) stage(sub + 1, cur ^ 1);

    f32x4 acc[4][2];
#pragma unroll
    for (int i = 0; i < 4; ++i) {
      acc[i][0] = (f32x4){0.f, 0.f, 0.f, 0.f};
      acc[i][1] = (f32x4){0.f, 0.f, 0.f, 0.f};
    }

    const int rl0 = wn * 32 + lr;
    const int rl1 = rl0 + 16;
#pragma unroll
    for (int ks = 0; ks < 8; ++ks) {
      short8 b0 = *(const short8*)&Bl[cur][rl0 * 256 + (((ks * 4 + lg) ^ (rl0 & 7)) << 3)];
      short8 b1 = *(const short8*)&Bl[cur][rl1 * 256 + (((ks * 4 + lg) ^ (rl1 & 7)) << 3)];
#pragma unroll
      for (int mt = 0; mt < 4; ++mt) {
        acc[mt][0] = __builtin_amdgcn_mfma_f32_16x16x32_bf16(a[mt][ks], b0, acc[mt][0], 0, 0, 0);
        acc[mt][1] = __builtin_amdgcn_mfma_f32_16x16x32_bf16(a[mt][ks], b1, acc[mt][1], 0, 0, 0);
      }
    }

    // ---- epilogue: per-wave LDS transpose -> coalesced float4 stores ----
    const int cg = (lane & 7) * 4;
    const int gc = sub * 64 + wn * 32 + cg;
    f32x4 bias4 = (f32x4){0.f, 0.f, 0.f, 0.f};
    if (gc < IN_DIM) bias4 = *(const f32x4*)&b_d2[gc];
    float* TBw = TB + wid * 512;
#pragma unroll
    for (int mt = 0; mt < 4; ++mt) {
#pragma unroll
      for (int nt = 0; nt < 2; ++nt)
#pragma unroll
        for (int r = 0; r < 4; ++r) {
          int row = lg * 4 + r;
          TBw[row * 32 + ((nt * 16 + lr) ^ (((row >> 2) & 1) << 4))] = acc[mt][nt][r];
        }
#pragma unroll
      for (int p = 0; p < 2; ++p) {
        int row = p * 8 + (lane >> 3);
        f32x4 v = *(const f32x4*)&TBw[row * 32 + (cg ^ (((row >> 2) & 1) << 4))];
        if (gc < IN_DIM) {
          int gr = m0 + wm * 64 + mt * 16 + row;
          *(f32x4*)&recon[(size_t)gr * IN_DIM + gc] = v + bias4;
        }
      }
    }
    __syncthreads();
    cur ^= 1;
  }
}

extern "C" void kernel_launch(void* const* d_in, const int* in_sizes, int n_in,
                              void* d_out, int out_size, void* d_ws, size_t ws_size,
                              hipStream_t stream) {
  const float* x     = (const float*)d_in[0];
  const int*   edge  = (const int*)d_in[1];
  const float* w_gcn = (const float*)d_in[2];
  const float* b_gcn = (const float*)d_in[3];
  const float* w_enc = (const float*)d_in[4];
  const float* b_enc = (const float*)d_in[5];
  const float* w_d1  = (const float*)d_in[6];
  const float* b_d1  = (const float*)d_in[7];
  const float* w_d2  = (const float*)d_in[8];
  const float* b_d2  = (const float*)d_in[9];
  float* out = (float*)d_out;
  (void)in_sizes; (void)n_in; (void)out_size; (void)ws_size;

  char* ws = (char*)d_ws;
  size_t o = 0;
  auto alloc = [&](size_t bytes) {
    char* p = ws + o;
    o += (bytes + 255) & ~(size_t)255;
    return p;
  };
  unsigned short* wpk  = (unsigned short*)alloc((size_t)K_STEPS * HIDDEN * 32 * 2);
  unsigned short* wd2t = (unsigned short*)alloc((size_t)WD2T_ROWS * HIDDEN * 2);
  float* h0p  = (float*)alloc((size_t)4 * N_NODES * HIDDEN * 4);
  float* h0   = (float*)alloc((size_t)N_NODES * HIDDEN * 4);
  float* hrel = (float*)alloc((size_t)N_NODES * HIDDEN * 4);
  unsigned short* hid2 = (unsigned short*)alloc((size_t)N_NODES * HIDDEN * 2);
  int* cnt    = (int*)alloc(N_NODES * 4);
  float* dinv = (float*)alloc(N_NODES * 4);
  int* offs   = (int*)alloc((N_NODES + 1) * 4);
  int* cursor = (int*)alloc(N_NODES * 4);
  int* csr    = (int*)alloc((size_t)N_EDGES * 4);

  const int* erow = edge;
  const int* ecol = edge + N_EDGES;

  hipMemsetAsync(cnt, 0, N_NODES * 4, stream);
  k_count<<<N_EDGES / 256, 256, 0, stream>>>(ecol, cnt);
  k_scan<<<1, 256, 0, stream>>>(cnt, offs, cursor);
  k_dinv<<<N_NODES / 256, 256, 0, stream>>>(cnt, dinv);
  k_fill<<<N_EDGES / 256, 256, 0, stream>>>(erow, ecol, cursor, csr);
  k_pack_wgcn<<<K_STEPS, 256, 0, stream>>>(w_gcn, wpk);
  k_twd2<<<WD2T_ROWS / 64, 256, 0, stream>>>(w_d2, wd2t);
  k_gemm1<<<dim3(N_NODES / 64, 4), 512, 0, stream>>>(x, wpk, h0p);
  k_sum<<<(N_NODES * HIDDEN / 4) / 256, 256, 0, stream>>>(h0p, h0);
  k_agg<<<N_NODES, 256, 0, stream>>>(h0, dinv, offs, csr, b_gcn, hrel);
  float* latent = out + RECON_ELEMS;
  k_enc<<<N_NODES / 4, 256, 0, stream>>>(hrel, w_enc, b_enc, latent);
  k_dec1<<<N_NODES / 4, 256, 0, stream>>>(latent, w_d1, b_d1, hid2);
  k_gemm3<<<dim3(N_NODES / 128, 8), 256, 0, stream>>>(hid2, wd2t, b_d2, out);
}